// Round 8
// baseline (274.983 us; speedup 1.0000x reference)
//
#include <hip/hip_runtime.h>
#include <hip/hip_bf16.h>
#include <hip/hip_fp8.h>

#define FEAT    256
#define KDIM    512   // FEAT + EMBED
#define EMBED   256
#define BATCH   50000
#define NSAMP   25
#define N_NODES 100000
#define NAN_FILL 0.01f

#define NTILE   48    // batch items per block (proven r0/r7 geometry)
#define IPW     12    // items per wave
#define LSTRIDE 520   // shorts per LDS row: 512 + 8 pad -> 260 words == 4 (mod 32)
                      // => B-frag ds_read_b128 start-bank = 4*(r+q): perfect 8-cycle tiling

typedef __attribute__((ext_vector_type(8))) short  short8;
typedef __attribute__((ext_vector_type(4))) float  floatx4;
typedef __attribute__((ext_vector_type(2))) float  float2v;
typedef __attribute__((ext_vector_type(4))) unsigned short ushort4v;
typedef __attribute__((ext_vector_type(8))) unsigned short ushort8v;
typedef __attribute__((ext_vector_type(4))) unsigned int   uint4v;
typedef __attribute__((ext_vector_type(4))) float  float4v;

#if __has_builtin(__builtin_amdgcn_cvt_pk_f32_fp8)
#define PK_FP8_DEC 1
#else
#define PK_FP8_DEC 0
#endif
#if __has_builtin(__builtin_amdgcn_cvt_pk_fp8_f32)
#define PK_FP8_ENC 1
#else
#define PK_FP8_ENC 0
#endif

// Non-temporal load: gathered lines have ZERO L1 reuse (each 64B line is fully
// consumed by the instruction that fetches it; rows never re-touched by this CU).
// NT bypasses L1 allocation -> relieves per-CU outstanding-miss resources.
#if __has_builtin(__builtin_nontemporal_load)
#define NTLOAD(p) __builtin_nontemporal_load(p)
#else
#define NTLOAD(p) (*(p))
#endif

__device__ inline unsigned short f2bf(float x) {
    __hip_bfloat16 h = __float2bfloat16(x);
    union { __hip_bfloat16 h; unsigned short u; } c; c.h = h;
    return c.u;
}
__device__ inline unsigned char f2fp8(float x) {
    __hip_fp8_e4m3 t(x);
    return (unsigned char)t.__x;
}
__device__ inline float fp8f(unsigned v) {
    __hip_fp8_e4m3 t; t.__x = (unsigned char)v;
    return (float)t;
}

// ---------------- Stage 0: features f32 -> fp8 table (25.6MB) + bf16 table (51.2MB) --
__global__ __launch_bounds__(256) void fconv8_kernel(
    const float* __restrict__ F, unsigned char* __restrict__ F8,
    unsigned short* __restrict__ Fb)
{
    const size_t i = ((size_t)blockIdx.x * 256 + threadIdx.x) * 8;
    float4v a = *(const float4v*)(F + i);
    float4v b = *(const float4v*)(F + i + 4);
#if PK_FP8_ENC
    unsigned w0 = (unsigned)__builtin_amdgcn_cvt_pk_fp8_f32(a[0], a[1], 0, false);
    w0 = (unsigned)__builtin_amdgcn_cvt_pk_fp8_f32(a[2], a[3], (int)w0, true);
    unsigned w1 = (unsigned)__builtin_amdgcn_cvt_pk_fp8_f32(b[0], b[1], 0, false);
    w1 = (unsigned)__builtin_amdgcn_cvt_pk_fp8_f32(b[2], b[3], (int)w1, true);
    uint2 o; o.x = w0; o.y = w1;
    *(uint2*)(F8 + i) = o;
#else
    union { unsigned char c[8]; uint2 v; } o;
    o.c[0] = f2fp8(a[0]); o.c[1] = f2fp8(a[1]); o.c[2] = f2fp8(a[2]); o.c[3] = f2fp8(a[3]);
    o.c[4] = f2fp8(b[0]); o.c[5] = f2fp8(b[1]); o.c[6] = f2fp8(b[2]); o.c[7] = f2fp8(b[3]);
    *(uint2*)(F8 + i) = o.v;
#endif
    ushort8v h;
    h[0] = f2bf(a[0]); h[1] = f2bf(a[1]); h[2] = f2bf(a[2]); h[3] = f2bf(a[3]);
    h[4] = f2bf(b[0]); h[5] = f2bf(b[1]); h[6] = f2bf(b[2]); h[7] = f2bf(b[3]);
    *(ushort8v*)(Fb + i) = h;
}

// ---------------- Stage 0b: W f32 -> bf16 ----------------
__global__ __launch_bounds__(256) void wconv_kernel(
    const float* __restrict__ W, unsigned short* __restrict__ Wb)
{
    const int i = blockIdx.x * 256 + threadIdx.x;   // grid sized exactly 256*512
    Wb[i] = f2bf(W[i]);
}

// ---------------- Fused: gather+mean -> LDS tile -> MFMA GEMM -> ReLU -> out ----------
// r7 structure (best: 88.6us) + round-8 deltas:
//   (a) NT loads on all gathered/streamed data (F8 rows, Fb self rows, indices)
//   (b) self rows read from pre-converted bf16 Fb (512B rows, half the bytes,
//       zero converts) instead of f32 F
// Phase 1: 4 items per wave concurrently, 16 lanes each; one uint4/lane = 4 full
//   fp8 rows per instruction; indices via vector loads + __shfl broadcast;
//   25 steps chunked 5x5, depth-2 A/B rotation, sched_barrier(0) fences.
// Phase 2: r0-proven MFMA GEMM (A=W from global/L2, B from LDS).
// MFMA 16x16x32 bf16 layouts (guide-verified):
//   A: lane holds A[m=lane&15][k=(lane>>4)*8+j]; B: B[k=(lane>>4)*8+j][n=lane&15]
//   D: row=(lane>>4)*4+reg, col=lane&15
__global__ __launch_bounds__(256, 3) void enc_kernel(
    const unsigned char* __restrict__ F8,   // [N_NODES, 256] fp8
    const unsigned short* __restrict__ Fb,  // [N_NODES, 256] bf16
    const unsigned short* __restrict__ Wb,  // [256, 512] bf16
    const int* __restrict__ nodes,
    const int* __restrict__ neigh,          // [BATCH, NSAMP]
    float* __restrict__ out)                // [256, BATCH] f32
{
    __shared__ unsigned short cl[NTILE * LSTRIDE];  // 49,920 B -> 3 blocks/CU

    const int lane = threadIdx.x & 63;
    const int wave = threadIdx.x >> 6;
    const int g = lane >> 4;                // group 0..3 (= q in GEMM phase)
    const int r = lane & 15;
    const int nbase = blockIdx.x * NTILE;

    // ---- Phase 1: grouped gather + mean into LDS (3 rounds x 4 items/wave) ----
    #pragma unroll
    for (int round = 0; round < IPW / 4; ++round) {
        const int b0 = nbase + wave * IPW + round * 4;
        int bg = b0 + g; if (bg >= BATCH) bg = BATCH - 1;   // dup work, stores same row

        // Index preload: lane g*16+j holds sample j (j<16) of item g; ihi covers 16..24.
        const int ilo = NTLOAD(&neigh[(size_t)bg * NSAMP + r]);
        const int ihi = NTLOAD(&neigh[(size_t)bg * NSAMP + (r > 8 ? 24 : 16 + r)]);
        const int nd  = nodes[bg];

        // Self rows (bf16, 512B each): 4 independent full-wave NT loads, issued early.
        ushort4v sv0, sv1, sv2, sv3;
        {
            const int n0 = __shfl(nd, 0),  n1 = __shfl(nd, 16);
            const int n2 = __shfl(nd, 32), n3 = __shfl(nd, 48);
            sv0 = NTLOAD((const ushort4v*)(Fb + (size_t)n0 * FEAT + lane * 4));
            sv1 = NTLOAD((const ushort4v*)(Fb + (size_t)n1 * FEAT + lane * 4));
            sv2 = NTLOAD((const ushort4v*)(Fb + (size_t)n2 * FEAT + lane * 4));
            sv3 = NTLOAD((const ushort4v*)(Fb + (size_t)n3 * FEAT + lane * 4));
        }

        float2v acc[8] = {};                // 16 f32: features [r*16, r*16+16) of item g

#define SHFL5(DST, C) do {                                                    \
        _Pragma("unroll")                                                     \
        for (int jj = 0; jj < 5; ++jj) {                                      \
            const int j_ = (C) * 5 + jj;                                      \
            DST[jj] = __shfl(j_ < 16 ? ilo : ihi,                             \
                             g * 16 + (j_ < 16 ? j_ : j_ - 16));              \
        }                                                                     \
    } while (0)

#define GATH5(WV, IDX) do {                                                   \
        _Pragma("unroll")                                                     \
        for (int jj = 0; jj < 5; ++jj)                                        \
            WV[jj] = NTLOAD((const uint4v*)(F8 + (size_t)IDX[jj] * FEAT + r * 16)); \
    } while (0)

#if PK_FP8_DEC
#define CONS5(WV) do {                                                        \
        _Pragma("unroll")                                                     \
        for (int jj = 0; jj < 5; ++jj) {                                      \
            _Pragma("unroll")                                                 \
            for (int d_ = 0; d_ < 4; ++d_) {                                  \
                const unsigned w_ = WV[jj][d_];                               \
                acc[d_ * 2]     += __builtin_amdgcn_cvt_pk_f32_fp8((int)w_, false); \
                acc[d_ * 2 + 1] += __builtin_amdgcn_cvt_pk_f32_fp8((int)w_, true);  \
            }                                                                 \
        }                                                                     \
    } while (0)
#else
#define CONS5(WV) do {                                                        \
        _Pragma("unroll")                                                     \
        for (int jj = 0; jj < 5; ++jj) {                                      \
            _Pragma("unroll")                                                 \
            for (int d_ = 0; d_ < 4; ++d_) {                                  \
                const unsigned w_ = WV[jj][d_];                               \
                acc[d_ * 2][0]     += fp8f(w_);                               \
                acc[d_ * 2][1]     += fp8f(w_ >> 8);                          \
                acc[d_ * 2 + 1][0] += fp8f(w_ >> 16);                         \
                acc[d_ * 2 + 1][1] += fp8f(w_ >> 24);                         \
            }                                                                 \
        }                                                                     \
    } while (0)
#endif

#define SB __builtin_amdgcn_sched_barrier(0)

        // Depth-2 chunk pipeline over 25 steps: issue c+1 while consuming c.
        int ixA[5], ixB[5];
        uint4v wvA[5], wvB[5];
        SHFL5(ixA, 0); GATH5(wvA, ixA);
        SHFL5(ixB, 1); GATH5(wvB, ixB);
        SB; CONS5(wvA);
        SHFL5(ixA, 2); GATH5(wvA, ixA);
        SB; CONS5(wvB);
        SHFL5(ixB, 3); GATH5(wvB, ixB);
        SB; CONS5(wvA);
        SHFL5(ixA, 4); GATH5(wvA, ixA);
        SB; CONS5(wvB);
        SB; CONS5(wvA);
#undef SHFL5
#undef GATH5
#undef CONS5
#undef SB

        // Stores: self rows (full-wave, bf16 pass-through, 4 items) ...
        const int lrow0 = wave * IPW + round * 4;
        {
            unsigned short* row;
            row = cl + (lrow0 + 0) * LSTRIDE; *(ushort4v*)(row + lane * 4) = sv0;
            row = cl + (lrow0 + 1) * LSTRIDE; *(ushort4v*)(row + lane * 4) = sv1;
            row = cl + (lrow0 + 2) * LSTRIDE; *(ushort4v*)(row + lane * 4) = sv2;
            row = cl + (lrow0 + 3) * LSTRIDE; *(ushort4v*)(row + lane * 4) = sv3;
        }
        // ... and neighbor mean: lane owns features [r*16, r*16+16) of item g.
        {
            const float inv = 1.0f / NSAMP;
            unsigned short* grow = cl + (lrow0 + g) * LSTRIDE + FEAT + r * 16;
            ushort8v m0, m1;
            #pragma unroll
            for (int k2 = 0; k2 < 4; ++k2) {
                m0[k2 * 2]     = f2bf(acc[k2][0] * inv);
                m0[k2 * 2 + 1] = f2bf(acc[k2][1] * inv);
                m1[k2 * 2]     = f2bf(acc[4 + k2][0] * inv);
                m1[k2 * 2 + 1] = f2bf(acc[4 + k2][1] * inv);
            }
            *(ushort8v*)grow       = m0;
            *(ushort8v*)(grow + 8) = m1;
        }
    }
    __syncthreads();

    // ---- Phase 2: MFMA GEMM from LDS tile (r0-proven, unchanged) ----
    const int mbase = wave * 64;
    const short* Wp = (const short*)Wb;
    const short* cp = (const short*)cl;

    floatx4 acc2[4][3] = {};

    for (int k = 0; k < KDIM; k += 32) {
        short8 afr[4], bfr[3];
        #pragma unroll
        for (int mt = 0; mt < 4; ++mt) {
            const short* p = Wp + (size_t)(mbase + mt * 16 + r) * KDIM + k + g * 8;
            afr[mt] = *(const short8*)p;
        }
        #pragma unroll
        for (int nt = 0; nt < 3; ++nt) {
            const short* p = cp + (nt * 16 + r) * LSTRIDE + k + g * 8;
            bfr[nt] = *(const short8*)p;
        }
        #pragma unroll
        for (int mt = 0; mt < 4; ++mt)
            #pragma unroll
            for (int nt = 0; nt < 3; ++nt)
                acc2[mt][nt] = __builtin_amdgcn_mfma_f32_16x16x32_bf16(
                    afr[mt], bfr[nt], acc2[mt][nt], 0, 0, 0);
    }

    // ---- Epilogue: ReLU + store ----
    #pragma unroll
    for (int mt = 0; mt < 4; ++mt) {
        #pragma unroll
        for (int nt = 0; nt < 3; ++nt) {
            const int col = nbase + nt * 16 + r;
            if (col < BATCH) {
                #pragma unroll
                for (int i = 0; i < 4; ++i) {
                    const int row = mbase + mt * 16 + g * 4 + i;
                    float v = acc2[mt][nt][i];
                    out[(size_t)row * BATCH + col] = v > 0.f ? v : 0.f;
                }
            }
        }
    }
}

extern "C" void kernel_launch(void* const* d_in, const int* in_sizes, int n_in,
                              void* d_out, int out_size, void* d_ws, size_t ws_size,
                              hipStream_t stream) {
    const float* features = (const float*)d_in[0];   // [100000, 256] f32
    const float* weight   = (const float*)d_in[1];   // [256, 512] f32
    const int*   nodes    = (const int*)d_in[2];     // [50000]
    const int*   neigh    = (const int*)d_in[3];     // [50000, 25]
    float* out = (float*)d_out;                      // [256, 50000] f32

    unsigned char*  F8 = (unsigned char*)d_ws;                            // 25.6 MB
    unsigned short* Wb = (unsigned short*)(F8 + (size_t)N_NODES * FEAT);  // +0.25 MB
    unsigned short* Fb = Wb + (size_t)EMBED * KDIM;                       // +51.2 MB

    fconv8_kernel<<<(N_NODES * FEAT) / (256 * 8), 256, 0, stream>>>(features, F8, Fb);
    wconv_kernel<<<(EMBED * KDIM) / 256, 256, 0, stream>>>(weight, Wb);

    const int nblocks = (BATCH + NTILE - 1) / NTILE;  // 1042
    enc_kernel<<<nblocks, 256, 0, stream>>>(F8, Fb, Wb, nodes, neigh, out);
}

// Round 9
// 248.784 us; speedup vs baseline: 1.1053x; 1.1053x over previous
//
#include <hip/hip_runtime.h>
#include <hip/hip_bf16.h>
#include <hip/hip_fp8.h>

#define FEAT    256
#define KDIM    512   // FEAT + EMBED
#define EMBED   256
#define BATCH   50000
#define NSAMP   25
#define N_NODES 100000
#define NAN_FILL 0.01f

#define NTILE   48    // batch items per block (proven r0/r7 geometry)
#define IPW     12    // items per wave
#define LSTRIDE 520   // shorts per LDS row: 512 + 8 pad -> 260 words == 4 (mod 32)
                      // => B-frag ds_read_b128 start-bank = 4*(r+q): perfect 8-cycle tiling

typedef __attribute__((ext_vector_type(8))) short  short8;
typedef __attribute__((ext_vector_type(4))) float  floatx4;
typedef __attribute__((ext_vector_type(2))) float  float2v;
typedef __attribute__((ext_vector_type(4))) unsigned short ushort4v;
typedef __attribute__((ext_vector_type(8))) unsigned short ushort8v;
typedef __attribute__((ext_vector_type(4))) unsigned int   uint4v;
typedef __attribute__((ext_vector_type(4))) float  float4v;

#if __has_builtin(__builtin_amdgcn_cvt_pk_f32_fp8)
#define PK_FP8_DEC 1
#else
#define PK_FP8_DEC 0
#endif
#if __has_builtin(__builtin_amdgcn_cvt_pk_fp8_f32)
#define PK_FP8_ENC 1
#else
#define PK_FP8_ENC 0
#endif

__device__ inline unsigned short f2bf(float x) {
    __hip_bfloat16 h = __float2bfloat16(x);
    union { __hip_bfloat16 h; unsigned short u; } c; c.h = h;
    return c.u;
}
__device__ inline unsigned char f2fp8(float x) {
    __hip_fp8_e4m3 t(x);
    return (unsigned char)t.__x;
}
__device__ inline float fp8f(unsigned v) {
    __hip_fp8_e4m3 t; t.__x = (unsigned char)v;
    return (float)t;
}

// ---------------- Stage 0: features f32 -> fp8 e4m3 table (25.6 MB) ----------------
// r8 lesson: NO nontemporal hints (nt is evict-first in L2 too; the F8 table has
// ~12.5x re-read reuse that L2/LLC must keep), and NO bf16 side table (fconv pays
// +51MB streaming writes > enc's ~4us saving).
__global__ __launch_bounds__(256) void fconv8_kernel(
    const float* __restrict__ F, unsigned char* __restrict__ F8)
{
    const size_t i = ((size_t)blockIdx.x * 256 + threadIdx.x) * 8;
    float4v a = *(const float4v*)(F + i);
    float4v b = *(const float4v*)(F + i + 4);
#if PK_FP8_ENC
    unsigned w0 = (unsigned)__builtin_amdgcn_cvt_pk_fp8_f32(a[0], a[1], 0, false);
    w0 = (unsigned)__builtin_amdgcn_cvt_pk_fp8_f32(a[2], a[3], (int)w0, true);
    unsigned w1 = (unsigned)__builtin_amdgcn_cvt_pk_fp8_f32(b[0], b[1], 0, false);
    w1 = (unsigned)__builtin_amdgcn_cvt_pk_fp8_f32(b[2], b[3], (int)w1, true);
    uint2 o; o.x = w0; o.y = w1;
    *(uint2*)(F8 + i) = o;
#else
    union { unsigned char c[8]; uint2 v; } o;
    o.c[0] = f2fp8(a[0]); o.c[1] = f2fp8(a[1]); o.c[2] = f2fp8(a[2]); o.c[3] = f2fp8(a[3]);
    o.c[4] = f2fp8(b[0]); o.c[5] = f2fp8(b[1]); o.c[6] = f2fp8(b[2]); o.c[7] = f2fp8(b[3]);
    *(uint2*)(F8 + i) = o.v;
#endif
}

// ---------------- Stage 0b: W f32 -> bf16 ----------------
__global__ __launch_bounds__(256) void wconv_kernel(
    const float* __restrict__ W, unsigned short* __restrict__ Wb)
{
    const int i = blockIdx.x * 256 + threadIdx.x;   // grid sized exactly 256*512
    Wb[i] = f2bf(W[i]);
}

// ---------------- Fused: gather+mean -> LDS tile -> MFMA GEMM -> ReLU -> out ----------
// r7 structure (best: 88.6us) with ONE change: depth-3 chunk pipeline (A,B,C live)
// so each CONS5 waits on a chunk issued ~2 full chunk-intervals (~700-900cy) earlier
// instead of ~1 (~300cy). Tests the residual exposed-latency component; if null,
// phase 1 is at the per-CU VMEM request-rate ceiling (r8 post-mortem arithmetic).
// Phase 1: 4 items per wave concurrently, 16 lanes each; one uint4/lane = 4 full
//   fp8 rows per instruction; indices via vector loads + __shfl broadcast;
//   25 steps chunked 5x5, depth-3 A/B/C rotation, sched_barrier(0) fences.
// Phase 2: r0-proven MFMA GEMM (A=W from global/L2, B from LDS).
// MFMA 16x16x32 bf16 layouts (guide-verified):
//   A: lane holds A[m=lane&15][k=(lane>>4)*8+j]; B: B[k=(lane>>4)*8+j][n=lane&15]
//   D: row=(lane>>4)*4+reg, col=lane&15
__global__ __launch_bounds__(256, 3) void enc_kernel(
    const float* __restrict__ F,            // [N_NODES, 256] f32
    const unsigned char* __restrict__ F8,   // [N_NODES, 256] fp8
    const unsigned short* __restrict__ Wb,  // [256, 512] bf16
    const int* __restrict__ nodes,
    const int* __restrict__ neigh,          // [BATCH, NSAMP]
    float* __restrict__ out)                // [256, BATCH] f32
{
    __shared__ unsigned short cl[NTILE * LSTRIDE];  // 49,920 B -> 3 blocks/CU

    const int lane = threadIdx.x & 63;
    const int wave = threadIdx.x >> 6;
    const int g = lane >> 4;                // group 0..3 (= q in GEMM phase)
    const int r = lane & 15;
    const int nbase = blockIdx.x * NTILE;

    // ---- Phase 1: grouped gather + mean into LDS (3 rounds x 4 items/wave) ----
    #pragma unroll
    for (int round = 0; round < IPW / 4; ++round) {
        const int b0 = nbase + wave * IPW + round * 4;
        int bg = b0 + g; if (bg >= BATCH) bg = BATCH - 1;   // dup work, stores same row

        // Index preload: lane g*16+j holds sample j (j<16) of item g; ihi covers 16..24.
        const int ilo = neigh[(size_t)bg * NSAMP + r];
        const int ihi = neigh[(size_t)bg * NSAMP + (r > 8 ? 24 : 16 + r)];
        const int nd  = nodes[bg];

        // Self rows: 4 independent full-wave loads (1KB each), issued early.
        float4v sv0, sv1, sv2, sv3;
        {
            const int n0 = __shfl(nd, 0),  n1 = __shfl(nd, 16);
            const int n2 = __shfl(nd, 32), n3 = __shfl(nd, 48);
            sv0 = *(const float4v*)(F + (size_t)n0 * FEAT + lane * 4);
            sv1 = *(const float4v*)(F + (size_t)n1 * FEAT + lane * 4);
            sv2 = *(const float4v*)(F + (size_t)n2 * FEAT + lane * 4);
            sv3 = *(const float4v*)(F + (size_t)n3 * FEAT + lane * 4);
        }

        float2v acc[8] = {};                // 16 f32: features [r*16, r*16+16) of item g

#define SHFL5(DST, C) do {                                                    \
        _Pragma("unroll")                                                     \
        for (int jj = 0; jj < 5; ++jj) {                                      \
            const int j_ = (C) * 5 + jj;                                      \
            DST[jj] = __shfl(j_ < 16 ? ilo : ihi,                             \
                             g * 16 + (j_ < 16 ? j_ : j_ - 16));              \
        }                                                                     \
    } while (0)

#define GATH5(WV, IDX) do {                                                   \
        _Pragma("unroll")                                                     \
        for (int jj = 0; jj < 5; ++jj)                                        \
            WV[jj] = *(const uint4v*)(F8 + (size_t)IDX[jj] * FEAT + r * 16);  \
    } while (0)

#if PK_FP8_DEC
#define CONS5(WV) do {                                                        \
        _Pragma("unroll")                                                     \
        for (int jj = 0; jj < 5; ++jj) {                                      \
            _Pragma("unroll")                                                 \
            for (int d_ = 0; d_ < 4; ++d_) {                                  \
                const unsigned w_ = WV[jj][d_];                               \
                acc[d_ * 2]     += __builtin_amdgcn_cvt_pk_f32_fp8((int)w_, false); \
                acc[d_ * 2 + 1] += __builtin_amdgcn_cvt_pk_f32_fp8((int)w_, true);  \
            }                                                                 \
        }                                                                     \
    } while (0)
#else
#define CONS5(WV) do {                                                        \
        _Pragma("unroll")                                                     \
        for (int jj = 0; jj < 5; ++jj) {                                      \
            _Pragma("unroll")                                                 \
            for (int d_ = 0; d_ < 4; ++d_) {                                  \
                const unsigned w_ = WV[jj][d_];                               \
                acc[d_ * 2][0]     += fp8f(w_);                               \
                acc[d_ * 2][1]     += fp8f(w_ >> 8);                          \
                acc[d_ * 2 + 1][0] += fp8f(w_ >> 16);                         \
                acc[d_ * 2 + 1][1] += fp8f(w_ >> 24);                         \
            }                                                                 \
        }                                                                     \
    } while (0)
#endif

#define SB __builtin_amdgcn_sched_barrier(0)

        // Depth-3 chunk pipeline over 25 steps: A,B,C live; each consume targets a
        // chunk issued 2 chunk-intervals earlier.
        int ixA[5], ixB[5], ixC[5];
        uint4v wvA[5], wvB[5], wvC[5];
        SHFL5(ixA, 0); GATH5(wvA, ixA);
        SHFL5(ixB, 1); GATH5(wvB, ixB);
        SHFL5(ixC, 2); GATH5(wvC, ixC);
        SB; CONS5(wvA);
        SHFL5(ixA, 3); GATH5(wvA, ixA);
        SB; CONS5(wvB);
        SHFL5(ixB, 4); GATH5(wvB, ixB);
        SB; CONS5(wvC);
        SB; CONS5(wvA);
        SB; CONS5(wvB);
#undef SHFL5
#undef GATH5
#undef CONS5
#undef SB

        // Stores: self rows (full-wave, 4 items) ...
        const int lrow0 = wave * IPW + round * 4;
        {
            ushort4v s;
            unsigned short* row;
            s[0]=f2bf(sv0[0]); s[1]=f2bf(sv0[1]); s[2]=f2bf(sv0[2]); s[3]=f2bf(sv0[3]);
            row = cl + (lrow0 + 0) * LSTRIDE; *(ushort4v*)(row + lane * 4) = s;
            s[0]=f2bf(sv1[0]); s[1]=f2bf(sv1[1]); s[2]=f2bf(sv1[2]); s[3]=f2bf(sv1[3]);
            row = cl + (lrow0 + 1) * LSTRIDE; *(ushort4v*)(row + lane * 4) = s;
            s[0]=f2bf(sv2[0]); s[1]=f2bf(sv2[1]); s[2]=f2bf(sv2[2]); s[3]=f2bf(sv2[3]);
            row = cl + (lrow0 + 2) * LSTRIDE; *(ushort4v*)(row + lane * 4) = s;
            s[0]=f2bf(sv3[0]); s[1]=f2bf(sv3[1]); s[2]=f2bf(sv3[2]); s[3]=f2bf(sv3[3]);
            row = cl + (lrow0 + 3) * LSTRIDE; *(ushort4v*)(row + lane * 4) = s;
        }
        // ... and neighbor mean: lane owns features [r*16, r*16+16) of item g.
        {
            const float inv = 1.0f / NSAMP;
            unsigned short* grow = cl + (lrow0 + g) * LSTRIDE + FEAT + r * 16;
            ushort8v m0, m1;
            #pragma unroll
            for (int k2 = 0; k2 < 4; ++k2) {
                m0[k2 * 2]     = f2bf(acc[k2][0] * inv);
                m0[k2 * 2 + 1] = f2bf(acc[k2][1] * inv);
                m1[k2 * 2]     = f2bf(acc[4 + k2][0] * inv);
                m1[k2 * 2 + 1] = f2bf(acc[4 + k2][1] * inv);
            }
            *(ushort8v*)grow       = m0;
            *(ushort8v*)(grow + 8) = m1;
        }
    }
    __syncthreads();

    // ---- Phase 2: MFMA GEMM from LDS tile (r0-proven, unchanged) ----
    const int mbase = wave * 64;
    const short* Wp = (const short*)Wb;
    const short* cp = (const short*)cl;

    floatx4 acc2[4][3] = {};

    for (int k = 0; k < KDIM; k += 32) {
        short8 afr[4], bfr[3];
        #pragma unroll
        for (int mt = 0; mt < 4; ++mt) {
            const short* p = Wp + (size_t)(mbase + mt * 16 + r) * KDIM + k + g * 8;
            afr[mt] = *(const short8*)p;
        }
        #pragma unroll
        for (int nt = 0; nt < 3; ++nt) {
            const short* p = cp + (nt * 16 + r) * LSTRIDE + k + g * 8;
            bfr[nt] = *(const short8*)p;
        }
        #pragma unroll
        for (int mt = 0; mt < 4; ++mt)
            #pragma unroll
            for (int nt = 0; nt < 3; ++nt)
                acc2[mt][nt] = __builtin_amdgcn_mfma_f32_16x16x32_bf16(
                    afr[mt], bfr[nt], acc2[mt][nt], 0, 0, 0);
    }

    // ---- Epilogue: ReLU + store ----
    #pragma unroll
    for (int mt = 0; mt < 4; ++mt) {
        #pragma unroll
        for (int nt = 0; nt < 3; ++nt) {
            const int col = nbase + nt * 16 + r;
            if (col < BATCH) {
                #pragma unroll
                for (int i = 0; i < 4; ++i) {
                    const int row = mbase + mt * 16 + g * 4 + i;
                    float v = acc2[mt][nt][i];
                    out[(size_t)row * BATCH + col] = v > 0.f ? v : 0.f;
                }
            }
        }
    }
}

extern "C" void kernel_launch(void* const* d_in, const int* in_sizes, int n_in,
                              void* d_out, int out_size, void* d_ws, size_t ws_size,
                              hipStream_t stream) {
    const float* features = (const float*)d_in[0];   // [100000, 256] f32
    const float* weight   = (const float*)d_in[1];   // [256, 512] f32
    const int*   nodes    = (const int*)d_in[2];     // [50000]
    const int*   neigh    = (const int*)d_in[3];     // [50000, 25]
    float* out = (float*)d_out;                      // [256, 50000] f32

    unsigned char* F8  = (unsigned char*)d_ws;                         // 25.6 MB
    unsigned short* Wb = (unsigned short*)(F8 + (size_t)N_NODES * FEAT); // +0.25 MB

    fconv8_kernel<<<(N_NODES * FEAT) / (256 * 8), 256, 0, stream>>>(features, F8);
    wconv_kernel<<<(EMBED * KDIM) / 256, 256, 0, stream>>>(weight, Wb);

    const int nblocks = (BATCH + NTILE - 1) / NTILE;  // 1042
    enc_kernel<<<nblocks, 256, 0, stream>>>(features, F8, Wb, nodes, neigh, out);
}